// Round 4
// baseline (1280.727 us; speedup 1.0000x reference)
//
#include <hip/hip_runtime.h>
#include <math.h>

#define M_ENT  50000
#define L_TOK  8
#define EDIM   256
#define BATCH  64
#define NHID   1024
#define GHOP   512
#define ROWS_PER_BLOCK ((M_ENT + GHOP - 1) / GHOP)   // 98

// ---------------------------------------------------------------------------
// u0 = query @ Qgate_w.T + b    (64x256, K=1024) — one wave per (b,e) pair
// ---------------------------------------------------------------------------
__global__ __launch_bounds__(256) void k_qgate(const float* __restrict__ q,
    const float* __restrict__ W, const float* __restrict__ bias,
    float* __restrict__ u_out)
{
    const int wg   = blockIdx.x * 4 + (threadIdx.x >> 6);   // 0..16383
    const int lane = threadIdx.x & 63;
    const int b = wg >> 8;     // batch
    const int e = wg & 255;    // output dim
    const float4* qp = (const float4*)(q + b * NHID);
    const float4* wp = (const float4*)(W + e * NHID);
    float s = 0.f;
    #pragma unroll
    for (int i = 0; i < 4; ++i) {
        float4 qa = qp[lane + 64 * i];
        float4 wa = wp[lane + 64 * i];
        s += qa.x * wa.x + qa.y * wa.y + qa.z * wa.z + qa.w * wa.w;
    }
    #pragma unroll
    for (int off = 32; off > 0; off >>= 1) s += __shfl_xor(s, off, 64);
    if (lane == 0) u_out[b * EDIM + e] = s + bias[e];
}

// ---------------------------------------------------------------------------
// m[j] = sum_t (entries[j][t] != 0) * wordemb[entries[j][t]]  — one wave per j
// ---------------------------------------------------------------------------
__global__ __launch_bounds__(256) void k_mem(const int* __restrict__ entries,
    const float* __restrict__ emb, float* __restrict__ m)
{
    const int j    = blockIdx.x * 4 + (threadIdx.x >> 6);
    const int lane = threadIdx.x & 63;
    float4 a = make_float4(0.f, 0.f, 0.f, 0.f);
    #pragma unroll
    for (int t = 0; t < L_TOK; ++t) {
        const int id = entries[j * L_TOK + t];      // wave-uniform
        if (id != 0) {
            float4 w = ((const float4*)(emb + (size_t)id * EDIM))[lane];
            a.x += w.x; a.y += w.y; a.z += w.z; a.w += w.w;
        }
    }
    ((float4*)(m + (size_t)j * EDIM))[lane] = a;
}

// ---------------------------------------------------------------------------
// Fused hop, BARRIER-FREE layout:
//   wave = 16 batches x full K=256;  lane = b4*4 + kg  (b4: batch-in-wave,
//   kg: 64-dim K-chunk).  Dot-product partial reduced with 2 __shfl_xor
//   within each 4-lane group — no LDS, no __syncthreads anywhere.
// Per m-row j: s_b = u[b]·m[j]/16, then acc += exp(s)*m[j], se += exp(s).
// |s| << 1 (sigma ~0.1) so exp without max-subtraction is exact-safe in f32.
// Each of the 4 waves covers a disjoint 16-batch group; m-row loads are
// 4 distinct broadcast addresses per instruction (L1/L2-resident row).
// ---------------------------------------------------------------------------
template <int WRITE_L>
__global__ __launch_bounds__(256, 2) void k_hop(
    const float* __restrict__ u_in, const float* __restrict__ m,
    float* __restrict__ pacc, float* __restrict__ psum,
    float* __restrict__ logits)
{
    const int wid  = threadIdx.x >> 6;     // 0..3: batch group
    const int lane = threadIdx.x & 63;
    const int b4   = lane >> 2;            // 0..15: batch within group
    const int kg   = lane & 3;             // 0..3: 64-dim K-chunk
    const int b    = wid * 16 + b4;        // 0..63: batch
    const int kb   = kg << 6;              // K base: 0,64,128,192

    // u chunk (64 floats) for (batch b, k-chunk kg) — persistent in registers
    float4 ur[16];
    {
        const float4* up = (const float4*)(u_in + b * EDIM + kb);
        #pragma unroll
        for (int i = 0; i < 16; ++i) ur[i] = up[i];
    }
    float4 acc[16];
    #pragma unroll
    for (int i = 0; i < 16; ++i) acc[i] = make_float4(0.f, 0.f, 0.f, 0.f);
    float se = 0.f;

    const int r0 = blockIdx.x * ROWS_PER_BLOCK;
    const int r1 = (r0 + ROWS_PER_BLOCK < M_ENT) ? (r0 + ROWS_PER_BLOCK) : M_ENT;

    for (int j = r0; j < r1; ++j) {
        const float4* mp = (const float4*)(m + (size_t)j * EDIM + kb);
        float4 mr[16];
        #pragma unroll
        for (int i = 0; i < 16; ++i) mr[i] = mp[i];

        float r = 0.f;
        #pragma unroll
        for (int i = 0; i < 16; ++i) {
            r += mr[i].x * ur[i].x; r += mr[i].y * ur[i].y;
            r += mr[i].z * ur[i].z; r += mr[i].w * ur[i].w;
        }
        // reduce across the 4 kg lanes of this batch's group
        r += __shfl_xor(r, 1, 64);
        r += __shfl_xor(r, 2, 64);
        const float s = r * 0.0625f;
        const float p = __expf(s);
        if (kg == 0) {
            se += p;
            if (WRITE_L) logits[(size_t)b * M_ENT + j] = s;
        }
        #pragma unroll
        for (int i = 0; i < 16; ++i) {
            acc[i].x += p * mr[i].x; acc[i].y += p * mr[i].y;
            acc[i].z += p * mr[i].z; acc[i].w += p * mr[i].w;
        }
    }

    // write partials (always, even for the empty-range tail block)
    float4* pa = (float4*)(pacc + (((size_t)blockIdx.x * BATCH + b) * EDIM + kb));
    #pragma unroll
    for (int i = 0; i < 16; ++i) pa[i] = acc[i];
    if (kg == 0) psum[blockIdx.x * BATCH + b] = se;
}

// ---------------------------------------------------------------------------
// Combine partials: u_out[b][e] = sum_g pacc[g][b][e] / sum_g psum[g][b]
// grid = 64 batches x 4 e-chunks, block = 512 (8 g-slices x 64 e-lanes)
// ---------------------------------------------------------------------------
__global__ __launch_bounds__(512) void k_comb(
    const float* __restrict__ pacc, const float* __restrict__ psum,
    float* __restrict__ u_out)
{
    const int b   = blockIdx.x >> 2;
    const int ec  = (blockIdx.x & 3) << 6;
    const int tid = threadIdx.x;
    const int gs  = tid >> 6;
    const int el  = tid & 63;

    __shared__ float sred[512];
    __shared__ float r2[8][64];

    sred[tid] = psum[(size_t)tid * BATCH + b];     // GHOP == 512 == blockDim
    __syncthreads();
    for (int off = 256; off > 0; off >>= 1) {
        if (tid < off) sred[tid] += sred[tid + off];
        __syncthreads();
    }
    const float inv = 1.0f / sred[0];

    float a = 0.f;
    const int e = ec + el;
    for (int g = gs; g < GHOP; g += 8)
        a += pacc[((size_t)g * BATCH + b) * EDIM + e];
    r2[gs][el] = a;
    __syncthreads();
    if (gs == 0) {
        float t = 0.f;
        #pragma unroll
        for (int q = 0; q < 8; ++q) t += r2[q][el];
        u_out[b * EDIM + e] = t * inv;
    }
}

// ---------------------------------------------------------------------------
extern "C" void kernel_launch(void* const* d_in, const int* in_sizes, int n_in,
                              void* d_out, int out_size, void* d_ws, size_t ws_size,
                              hipStream_t stream)
{
    const int*   entries = (const int*)  d_in[0];
    const float* query   = (const float*)d_in[1];
    const float* wemb    = (const float*)d_in[2];
    const float* Qw      = (const float*)d_in[3];
    const float* Qb      = (const float*)d_in[4];

    float* out_u = (float*)d_out;                    // [64][256]
    float* out_l = (float*)d_out + BATCH * EDIM;     // [64][50000]

    float* ws   = (float*)d_ws;
    float* m    = ws;                                // 12,800,000 f
    float* u_a  = m + (size_t)M_ENT * EDIM;          // 16384 f
    float* u_b  = u_a + BATCH * EDIM;                // 16384 f
    float* psum = u_b + BATCH * EDIM;                // 32768 f
    float* pacc = psum + GHOP * BATCH;               // 8,388,608 f   (~85 MB total)

    k_qgate<<<4096, 256, 0, stream>>>(query, Qw, Qb, u_a);
    k_mem<<<M_ENT / 4, 256, 0, stream>>>(entries, wemb, m);

    k_hop<0><<<GHOP, 256, 0, stream>>>(u_a, m, pacc, psum, nullptr);
    k_comb<<<256, 512, 0, stream>>>(pacc, psum, u_b);

    k_hop<0><<<GHOP, 256, 0, stream>>>(u_b, m, pacc, psum, nullptr);
    k_comb<<<256, 512, 0, stream>>>(pacc, psum, u_a);

    k_hop<1><<<GHOP, 256, 0, stream>>>(u_a, m, pacc, psum, out_l);
    k_comb<<<256, 512, 0, stream>>>(pacc, psum, out_u);
}

// Round 14
// 518.138 us; speedup vs baseline: 2.4718x; 2.4718x over previous
//
#include <hip/hip_runtime.h>
#include <math.h>

#define M_ENT  50000
#define L_TOK  8
#define EDIM   256
#define BATCH  64
#define NHID   1024

#define HOP_BLOCKS  256
#define HOP_THREADS 1024                 // 16 waves
#define NT          64                   // j-tile per block-iteration
#define NTILES      ((M_ENT + NT - 1) / NT)   // 782

typedef __attribute__((address_space(3))) unsigned int lds_u32;
typedef const __attribute__((address_space(1))) unsigned int glob_u32;

__device__ __forceinline__ void load_lds16(const float* g, float* l) {
    __builtin_amdgcn_global_load_lds((glob_u32*)g, (lds_u32*)l, 16, 0, 0);
}

// ---------------------------------------------------------------------------
// u0 = query @ Qgate_w.T + b    (64x256, K=1024) — one wave per (b,e) pair
// ---------------------------------------------------------------------------
__global__ __launch_bounds__(256) void k_qgate(const float* __restrict__ q,
    const float* __restrict__ W, const float* __restrict__ bias,
    float* __restrict__ u_out)
{
    const int wg   = blockIdx.x * 4 + (threadIdx.x >> 6);   // 0..16383
    const int lane = threadIdx.x & 63;
    const int b = wg >> 8;     // batch
    const int e = wg & 255;    // output dim
    const float4* qp = (const float4*)(q + b * NHID);
    const float4* wp = (const float4*)(W + e * NHID);
    float s = 0.f;
    #pragma unroll
    for (int i = 0; i < 4; ++i) {
        float4 qa = qp[lane + 64 * i];
        float4 wa = wp[lane + 64 * i];
        s += qa.x * wa.x + qa.y * wa.y + qa.z * wa.z + qa.w * wa.w;
    }
    #pragma unroll
    for (int off = 32; off > 0; off >>= 1) s += __shfl_xor(s, off, 64);
    if (lane == 0) u_out[b * EDIM + e] = s + bias[e];
}

// ---------------------------------------------------------------------------
// m[j] = sum_t (entries[j][t] != 0) * wordemb[entries[j][t]]  — one wave per j
// ---------------------------------------------------------------------------
__global__ __launch_bounds__(256) void k_mem(const int* __restrict__ entries,
    const float* __restrict__ emb, float* __restrict__ m)
{
    const int j    = blockIdx.x * 4 + (threadIdx.x >> 6);
    const int lane = threadIdx.x & 63;
    float4 a = make_float4(0.f, 0.f, 0.f, 0.f);
    #pragma unroll
    for (int t = 0; t < L_TOK; ++t) {
        const int id = entries[j * L_TOK + t];      // wave-uniform
        if (id != 0) {
            float4 w = ((const float4*)(emb + (size_t)id * EDIM))[lane];
            a.x += w.x; a.y += w.y; a.z += w.z; a.w += w.w;
        }
    }
    ((float4*)(m + (size_t)j * EDIM))[lane] = a;
}

// ---------------------------------------------------------------------------
// Fused hop, LDS-staged register-tiled version.
//   Block = 1024 threads (16 waves), grid-strides over 64-row m tiles.
//   LDS: mlds[64][256] (tile, broadcast-read only, staged via global_load_lds)
//        ulds[64][260]  (u, padded; b128 reads land 8 acc/bank = floor)
//        plds[64][64]   (softmax numerators p[j][b])
//   Phase 1 (per tile): wave w owns j = w*4..w*4+3; lane = batch b.
//     k-outer loop: 1 u float4 read (reused 4 j) + 4 m broadcasts + 16 FMA.
//   Phase 2: wave w owns e-range [16w,16w+16); contract over all 64 j:
//     p from plds (in-lane), m broadcast, 16 independent FMA accs (16 VGPR).
//   exp without max-subtraction: |s| <~ 0.6 (sigma 0.105), exact-safe in f32.
// ---------------------------------------------------------------------------
template <int WRITE_L>
__global__ __launch_bounds__(HOP_THREADS, 4) void k_hop2(
    const float* __restrict__ u_in, const float* __restrict__ m,
    float* __restrict__ paccT, float* __restrict__ psum,
    float* __restrict__ logitsT)
{
    __shared__ float mlds[NT][EDIM];       // 65536 B
    __shared__ float ulds[BATCH][260];     // 66560 B
    __shared__ float plds[NT][BATCH];      // 16384 B   -> 148480 B total

    const int tid  = threadIdx.x;
    const int w    = tid >> 6;            // wave 0..15
    const int lane = tid & 63;            // = batch b in compute phases

    // ---- stage u once: 16384 floats = 4096 float4; 1024 threads x 4 each
    //      (round-5 fix: previous version staged only 1/4 of u -> NaN)
    #pragma unroll
    for (int i = 0; i < 4; ++i) {
        const int idx = tid + i * 1024;        // float4 index, 0..4095
        const int row = idx >> 6;              // 64 float4 per row
        const int ch  = (idx & 63) << 2;
        *(float4*)&ulds[row][ch] = *(const float4*)(u_in + row * EDIM + ch);
    }

    float4 acc[4];
    #pragma unroll
    for (int i = 0; i < 4; ++i) acc[i] = make_float4(0.f, 0.f, 0.f, 0.f);
    float se = 0.f;
    const int e0 = w << 4;                // phase-2 e-range base

    for (int t = blockIdx.x; t < NTILES; t += HOP_BLOCKS) {
        const int j0  = t * NT;
        const int rem = M_ENT - j0;       // >=1; <NT only on the last tile

        __syncthreads();   // prev tile's phase2 done (and u-stage on iter 0)

        // ---- stage m tile: wave w stages rows it*16+w (1KB each, linear dest)
        #pragma unroll
        for (int it = 0; it < 4; ++it) {
            const int row = it * 16 + w;
            int j = j0 + row; if (j >= M_ENT) j = M_ENT - 1;   // clamp (tail)
            load_lds16(m + (size_t)j * EDIM + (lane << 2), &mlds[row][0]);
        }
        __syncthreads();   // drains vmcnt: tile fully staged

        // ---- phase 1: s[b][j] for this wave's 4 j
        float s[4] = {0.f, 0.f, 0.f, 0.f};
        const int jb = w << 2;
        #pragma unroll 8
        for (int k4 = 0; k4 < 64; ++k4) {
            const float4 uk = *(const float4*)&ulds[lane][k4 << 2];
            #pragma unroll
            for (int i = 0; i < 4; ++i) {
                const float4 mb = *(const float4*)&mlds[jb + i][k4 << 2];
                s[i] = fmaf(uk.x, mb.x, s[i]);
                s[i] = fmaf(uk.y, mb.y, s[i]);
                s[i] = fmaf(uk.z, mb.z, s[i]);
                s[i] = fmaf(uk.w, mb.w, s[i]);
            }
        }
        #pragma unroll
        for (int i = 0; i < 4; ++i) {
            const int jl = jb + i;
            const float sv = s[i] * 0.0625f;
            const float p  = (jl < rem) ? __expf(sv) : 0.f;
            se += p;
            plds[jl][lane] = p;
            if (WRITE_L && (jl < rem))
                logitsT[(size_t)(j0 + jl) * BATCH + lane] = sv;
        }
        __syncthreads();   // p visible to all waves

        // ---- phase 2: acc[b][e0..e0+15] += sum_j p[b][j] * m[j][e]
        #pragma unroll 8
        for (int j = 0; j < NT; ++j) {
            const float pv = plds[j][lane];
            #pragma unroll
            for (int i = 0; i < 4; ++i) {
                const float4 mb = *(const float4*)&mlds[j][e0 + (i << 2)];
                acc[i].x = fmaf(pv, mb.x, acc[i].x);
                acc[i].y = fmaf(pv, mb.y, acc[i].y);
                acc[i].z = fmaf(pv, mb.z, acc[i].z);
                acc[i].w = fmaf(pv, mb.w, acc[i].w);
            }
        }
    }

    // ---- write partials: paccT[blk][e][b] (coalesced), se via LDS reduce
    #pragma unroll
    for (int i = 0; i < 4; ++i) {
        const size_t base = ((size_t)blockIdx.x * EDIM + e0 + (i << 2)) * BATCH + lane;
        paccT[base            ] = acc[i].x;
        paccT[base + BATCH    ] = acc[i].y;
        paccT[base + BATCH * 2] = acc[i].z;
        paccT[base + BATCH * 3] = acc[i].w;
    }
    __syncthreads();               // phase-2 p reads done; reuse plds
    plds[w][lane] = se;
    __syncthreads();
    if (w == 0) {
        float tot = 0.f;
        #pragma unroll
        for (int q = 0; q < 16; ++q) tot += plds[q][lane];
        psum[blockIdx.x * BATCH + lane] = tot;
    }
}

// ---------------------------------------------------------------------------
// Combine: u_out[b][e] = sum_g paccT[g][e][b] / sum_g psum[g][b]
// grid = 256 blocks (one per e), 256 threads (4 g-slices x 64 b)
// ---------------------------------------------------------------------------
__global__ __launch_bounds__(256) void k_comb2(
    const float* __restrict__ paccT, const float* __restrict__ psum,
    float* __restrict__ u_out)
{
    const int e  = blockIdx.x;
    const int b  = threadIdx.x & 63;
    const int gq = threadIdx.x >> 6;
    __shared__ float rn[4][64], rd[4][64];
    float num = 0.f, den = 0.f;
    for (int g = gq; g < HOP_BLOCKS; g += 4) {
        num += paccT[((size_t)g * EDIM + e) * BATCH + b];
        den += psum[g * BATCH + b];
    }
    rn[gq][b] = num; rd[gq][b] = den;
    __syncthreads();
    if (threadIdx.x < 64) {
        const float n = rn[0][b] + rn[1][b] + rn[2][b] + rn[3][b];
        const float d = rd[0][b] + rd[1][b] + rd[2][b] + rd[3][b];
        u_out[b * EDIM + e] = n / d;
    }
}

// ---------------------------------------------------------------------------
// Transpose logitsT[j][b] -> out[b][j]
// ---------------------------------------------------------------------------
__global__ __launch_bounds__(256) void k_tr(
    const float* __restrict__ lt, float* __restrict__ out)
{
    __shared__ float sm[64][65];
    const int j0 = blockIdx.x * 64;
    const int c  = threadIdx.x & 63;
    const int r4 = threadIdx.x >> 6;
    #pragma unroll
    for (int it = 0; it < 16; ++it) {
        const int r = it * 4 + r4;
        const int j = j0 + r;
        sm[r][c] = (j < M_ENT) ? lt[(size_t)j * BATCH + c] : 0.f;
    }
    __syncthreads();
    #pragma unroll
    for (int it = 0; it < 16; ++it) {
        const int b = it * 4 + r4;
        const int j = j0 + c;
        if (j < M_ENT) out[(size_t)b * M_ENT + j] = sm[c][b];
    }
}

// ---------------------------------------------------------------------------
extern "C" void kernel_launch(void* const* d_in, const int* in_sizes, int n_in,
                              void* d_out, int out_size, void* d_ws, size_t ws_size,
                              hipStream_t stream)
{
    const int*   entries = (const int*)  d_in[0];
    const float* query   = (const float*)d_in[1];
    const float* wemb    = (const float*)d_in[2];
    const float* Qw      = (const float*)d_in[3];
    const float* Qb      = (const float*)d_in[4];

    float* out_u = (float*)d_out;                    // [64][256]
    float* out_l = (float*)d_out + BATCH * EDIM;     // [64][50000]

    float* ws      = (float*)d_ws;
    float* m       = ws;                                   // 12,800,000 f
    float* u_a     = m + (size_t)M_ENT * EDIM;             // 16384 f
    float* u_b     = u_a + BATCH * EDIM;                   // 16384 f
    float* psum    = u_b + BATCH * EDIM;                   // 16384 f
    float* paccT   = psum + HOP_BLOCKS * BATCH;            // 4,194,304 f
    float* logitsT = paccT + (size_t)HOP_BLOCKS * EDIM * BATCH; // 3,203,072 f
    // total ~81 MB

    k_qgate<<<4096, 256, 0, stream>>>(query, Qw, Qb, u_a);
    k_mem<<<M_ENT / 4, 256, 0, stream>>>(entries, wemb, m);

    k_hop2<0><<<HOP_BLOCKS, HOP_THREADS, 0, stream>>>(u_a, m, paccT, psum, nullptr);
    k_comb2<<<EDIM, 256, 0, stream>>>(paccT, psum, u_b);

    k_hop2<0><<<HOP_BLOCKS, HOP_THREADS, 0, stream>>>(u_b, m, paccT, psum, nullptr);
    k_comb2<<<EDIM, 256, 0, stream>>>(paccT, psum, u_a);

    k_hop2<1><<<HOP_BLOCKS, HOP_THREADS, 0, stream>>>(u_a, m, paccT, psum, logitsT);
    k_comb2<<<EDIM, 256, 0, stream>>>(paccT, psum, out_u);

    k_tr<<<NTILES, 256, 0, stream>>>(logitsT, out_l);
}